// Round 7
// baseline (860.792 us; speedup 1.0000x reference)
//
#include <hip/hip_runtime.h>
#include <hip/hip_bf16.h>
#include <hip/hip_cooperative_groups.h>

namespace cg = cooperative_groups;

#define N_NODES 50000
#define N_EDGES 800000
#define FD 128
#define N_GRAPHS 256
#define NPART 6250   // N_NODES / 8 (nodes per XCD partition)

typedef unsigned short u16;
typedef short bf16x8 __attribute__((ext_vector_type(8)));
typedef float f32x4 __attribute__((ext_vector_type(4)));

__device__ __forceinline__ u16 f2bf(float v) {
    __hip_bfloat16 h = __float2bfloat16(v);
    union { __hip_bfloat16 hh; u16 u; } c; c.hh = h; return c.u;
}
__device__ __forceinline__ float bf2f(u16 r) {
    return __uint_as_float(((unsigned int)r) << 16);
}

// ---------------------------------------------------------------- CSR build: ONE cooperative kernel
// phase A: zero degcnt/bnbuf/pooled | B: count (XCD-partitioned atomics) | C: chunk sums
// D: offsets (redundant bsum scan + local scan) | E: fill. Phases = proven round-5 kernel bodies.
__global__ __launch_bounds__(256) void csr_coop_k(const int* __restrict__ src,
                                                  const int* __restrict__ dst,
                                                  int* __restrict__ cnt,
                                                  int* __restrict__ bsum,
                                                  int* __restrict__ offs,
                                                  int* __restrict__ cur,
                                                  int* __restrict__ edst,
                                                  float* __restrict__ bnbuf,
                                                  float* __restrict__ pooled,
                                                  int E, int M, int NB) {
    cg::grid_group grid = cg::this_grid();
    int tid = threadIdx.x;
    int bid = blockIdx.x;
    int gsz = gridDim.x * 256;
    int gidx = bid * 256 + tid;
    __shared__ int l[256];
    __shared__ int bs[256];

    // ---- phase A: zero
    for (int i = gidx; i < M; i += gsz) cnt[i] = 0;
    if (gidx < 512) bnbuf[gidx] = 0.f;
    for (int i = gidx; i < N_GRAPHS * FD; i += gsz) pooled[i] = 0.f;
    grid.sync();

    // ---- phase B: count degrees
    {
        int part = bid & 7;
        int lo = part * NPART, hi = lo + NPART;
        int stride = (gridDim.x >> 3) * 256;
        for (int e = (bid >> 3) * 256 + tid; e < E; e += stride) {
            int s = src[e];
            if (s >= lo && s < hi) atomicAdd(&cnt[s], 1);
        }
    }
    grid.sync();

    // ---- phase C: per-256-chunk sums
    for (int c = bid; c < NB; c += gridDim.x) {
        int i = c * 256 + tid;
        int v = (i < M) ? cnt[i] : 0;
        l[tid] = v;
        __syncthreads();
        for (int s = 128; s > 0; s >>= 1) {
            if (tid < s) l[tid] += l[tid + s];
            __syncthreads();
        }
        if (tid == 0) bsum[c] = l[0];
        __syncthreads();
    }
    grid.sync();

    // ---- phase D: offsets
    for (int c = bid; c < NB; c += gridDim.x) {
        bs[tid] = (tid < NB) ? bsum[tid] : 0;
        __syncthreads();
        for (int off = 1; off < 256; off <<= 1) {
            int t = (tid >= off) ? bs[tid - off] : 0;
            __syncthreads();
            bs[tid] += t;
            __syncthreads();
        }
        int base = (c == 0) ? 0 : bs[c - 1];
        int i = c * 256 + tid;
        int v = (i < M) ? cnt[i] : 0;
        l[tid] = v;
        __syncthreads();
        for (int off = 1; off < 256; off <<= 1) {
            int t = (tid >= off) ? l[tid - off] : 0;
            __syncthreads();
            l[tid] += t;
            __syncthreads();
        }
        int excl = l[tid] - v + base;
        if (i < M) { offs[i] = excl; cur[i] = excl; }
        if (i == M - 1) offs[M] = excl + v;
        __syncthreads();
    }
    grid.sync();

    // ---- phase E: fill CSR
    {
        int part = bid & 7;
        int lo = part * NPART, hi = lo + NPART;
        int stride = (gridDim.x >> 3) * 256;
        for (int e = (bid >> 3) * 256 + tid; e < E; e += stride) {
            int s = src[e];
            if (s >= lo && s < hi) {
                int p = atomicAdd(&cur[s], 1);
                edst[p] = dst[e];
            }
        }
    }
}

// ---------------------------------------------------------------- classic CSR path (fallback only)
__global__ __launch_bounds__(256) void zero_k(int* __restrict__ cnt, float* __restrict__ bnbuf,
                                              float* __restrict__ pooled, int M) {
    int i = blockIdx.x * 256 + threadIdx.x;
    int gsz = gridDim.x * 256;
    for (int k = i; k < M; k += gsz) cnt[k] = 0;
    if (i < 512) bnbuf[i] = 0.f;
    for (int k = i; k < N_GRAPHS * FD; k += gsz) pooled[k] = 0.f;
}
__global__ __launch_bounds__(256) void count_deg_part_k(const int* __restrict__ src,
                                                        int* __restrict__ cnt, int E) {
    int part = blockIdx.x & 7;
    int lo = part * NPART, hi = lo + NPART;
    int stride = (gridDim.x >> 3) * 256;
    for (int e = (blockIdx.x >> 3) * 256 + threadIdx.x; e < E; e += stride) {
        int s = src[e];
        if (s >= lo && s < hi) atomicAdd(&cnt[s], 1);
    }
}
__global__ __launch_bounds__(256) void fill_csr_part_k(const int* __restrict__ src,
                                                       const int* __restrict__ dst,
                                                       int* __restrict__ cur,
                                                       int* __restrict__ edst, int E) {
    int part = blockIdx.x & 7;
    int lo = part * NPART, hi = lo + NPART;
    int stride = (gridDim.x >> 3) * 256;
    for (int e = (blockIdx.x >> 3) * 256 + threadIdx.x; e < E; e += stride) {
        int s = src[e];
        if (s >= lo && s < hi) {
            int p = atomicAdd(&cur[s], 1);
            edst[p] = dst[e];
        }
    }
}
__global__ __launch_bounds__(256) void scan1_k(const int* __restrict__ cnt,
                                               int* __restrict__ bsum, int M) {
    int i = blockIdx.x * 256 + threadIdx.x;
    int v = (i < M) ? cnt[i] : 0;
    __shared__ int l[256];
    l[threadIdx.x] = v;
    __syncthreads();
    for (int s = 128; s > 0; s >>= 1) {
        if (threadIdx.x < s) l[threadIdx.x] += l[threadIdx.x + s];
        __syncthreads();
    }
    if (threadIdx.x == 0) bsum[blockIdx.x] = l[0];
}
__global__ __launch_bounds__(256) void scan3_k(const int* __restrict__ cnt,
                                               const int* __restrict__ bsum,
                                               int* __restrict__ offs,
                                               int* __restrict__ cur, int M, int NB) {
    int i = blockIdx.x * 256 + threadIdx.x;
    int tid = threadIdx.x;
    __shared__ int bs[256];
    bs[tid] = (tid < NB) ? bsum[tid] : 0;
    __syncthreads();
    for (int off = 1; off < 256; off <<= 1) {
        int t = (tid >= off) ? bs[tid - off] : 0;
        __syncthreads();
        bs[tid] += t;
        __syncthreads();
    }
    int base = (blockIdx.x == 0) ? 0 : bs[blockIdx.x - 1];
    int v = (i < M) ? cnt[i] : 0;
    __shared__ int l[256];
    l[tid] = v;
    __syncthreads();
    for (int off = 1; off < 256; off <<= 1) {
        int t = (tid >= off) ? l[tid - off] : 0;
        __syncthreads();
        l[tid] += t;
        __syncthreads();
    }
    int excl = l[tid] - v + base;
    if (i < M) { offs[i] = excl; cur[i] = excl; }
    if (i == M - 1) offs[M] = excl + v;
}

// ---------------------------------------------------------------- MFMA GEMM + dots (unchanged)
__global__ __launch_bounds__(256) void gemm_mfma_k(const float* __restrict__ Xf,
                                                   const u16* __restrict__ Xb,
                                                   int use_f32,
                                                   const float* __restrict__ W,
                                                   const float* __restrict__ sums,
                                                   const float* __restrict__ sumsq,
                                                   const float* __restrict__ g,
                                                   const float* __restrict__ b,
                                                   float invN, int haveBN,
                                                   const float* __restrict__ avec,
                                                   u16* __restrict__ Hb,
                                                   float* __restrict__ es,
                                                   float* __restrict__ ed, int M) {
    __shared__ u16 As[64][136];   // +8 pad: 2-way bank alias only
    __shared__ u16 Bs[128][136];
    __shared__ float cv[128];
    __shared__ float scsh[256];   // phase A: sc[0..128) sh[128..256); later reused as cvpart[256]
    int tid = threadIdx.x;
    int row0 = blockIdx.x * 64;

    if (haveBN) {
        if (tid < 128) {
            float mu = sums[tid] * invN;
            float var = sumsq[tid] * invN - mu * mu;
            float sc = g[tid] * rsqrtf(var + 1e-5f);
            scsh[tid] = sc;
            scsh[128 + tid] = b[tid] - mu * sc;
        }
        __syncthreads();
        float cvp = 0.f;
#pragma unroll 8
        for (int i = 0; i < 64; i++) {
            int idx = i * 256 + tid;
            int k = idx >> 7;           // wave-uniform: 2i + (tid>>7)
            int n = idx & 127;
            float wv = W[idx];          // coalesced
            Bs[n][k] = f2bf(scsh[k] * wv);
            cvp += scsh[128 + k] * wv;
        }
        __syncthreads();                // scsh reads done before aliasing as cvpart
        scsh[tid] = cvp;
        __syncthreads();
        if (tid < 128) cv[tid] = scsh[tid] + scsh[tid + 128];
    } else {
#pragma unroll 8
        for (int i = 0; i < 64; i++) {
            int idx = i * 256 + tid;
            Bs[idx & 127][idx >> 7] = f2bf(W[idx]);
        }
        if (tid < 128) cv[tid] = 0.f;
    }

    {
        int r = tid >> 2, k0 = (tid & 3) * 32;
        int grow = row0 + r;
        if (grow < M) {
            if (use_f32) {
                const float4* s = (const float4*)(Xf + (size_t)grow * FD + k0);
#pragma unroll
                for (int u = 0; u < 8; u++) {
                    float4 v = s[u];
                    ushort4 o;
                    o.x = f2bf(v.x); o.y = f2bf(v.y); o.z = f2bf(v.z); o.w = f2bf(v.w);
                    *(ushort4*)&As[r][k0 + u * 4] = o;
                }
            } else {
                const uint4* s = (const uint4*)(Xb + (size_t)grow * FD + k0);
#pragma unroll
                for (int u = 0; u < 4; u++) *(uint4*)&As[r][k0 + u * 8] = s[u];
            }
        } else {
            uint4 z = make_uint4(0, 0, 0, 0);
#pragma unroll
            for (int u = 0; u < 4; u++) *(uint4*)&As[r][k0 + u * 8] = z;
        }
    }
    __syncthreads();

    int wave = tid >> 6, lane = tid & 63;
    int quad = lane >> 4, n16 = lane & 15;
    int rbase = wave * 16;
    f32x4 acc[8];
    f32x4 zz = {0.f, 0.f, 0.f, 0.f};
#pragma unroll
    for (int t = 0; t < 8; t++) acc[t] = zz;

#pragma unroll
    for (int kk = 0; kk < 128; kk += 32) {
        bf16x8 a = *(const bf16x8*)&As[rbase + n16][kk + quad * 8];
#pragma unroll
        for (int t = 0; t < 8; t++) {
            bf16x8 bb = *(const bf16x8*)&Bs[t * 16 + n16][kk + quad * 8];
            acc[t] = __builtin_amdgcn_mfma_f32_16x16x32_bf16(a, bb, acc[t], 0, 0, 0);
        }
    }

    float sas[8], sad[8];
#pragma unroll
    for (int t = 0; t < 8; t++) {
        sas[t] = avec[t * 16 + n16];
        sad[t] = avec[128 + t * 16 + n16];
    }

#pragma unroll
    for (int reg = 0; reg < 4; reg++) {
        int grow = row0 + rbase + quad * 4 + reg;
        float vals[8];
        float ps = 0.f, pd = 0.f;
#pragma unroll
        for (int t = 0; t < 8; t++) {
            float v = acc[t][reg] + cv[t * 16 + n16];
            vals[t] = v;
            ps += v * sas[t];
            pd += v * sad[t];
        }
#pragma unroll
        for (int o = 8; o > 0; o >>= 1) { ps += __shfl_xor(ps, o); pd += __shfl_xor(pd, o); }
        if (grow < M) {
            if (n16 == 0) { es[grow] = ps; ed[grow] = pd; }
#pragma unroll
            for (int t = 0; t < 8; t++)
                Hb[(size_t)grow * FD + t * 16 + n16] = f2bf(vals[t]);
        }
    }
}

// ---------------------------------------------------------------- fused aggregation (R6 proven:
// lane-quartered, 7 args, no atomics)
__global__ __launch_bounds__(256) void agg_k(const u16* __restrict__ Hb,
                                             const float* __restrict__ es_,
                                             const float* __restrict__ ed_,
                                             const int* __restrict__ offs,
                                             const int* __restrict__ edst,
                                             u16* __restrict__ Out, int M) {
    int node = __builtin_amdgcn_readfirstlane((int)((blockIdx.x * blockDim.x + threadIdx.x) >> 6));
    int lane = threadIdx.x & 63;
    if (node >= M) return;
    int s0 = offs[node], s1 = offs[node + 1];
    float esv = es_[node];
    int q = lane >> 4;       // edge slot within group
    int f16 = lane & 15;     // 16B-chunk index within row
    const uint4* Hq = (const uint4*)Hb;   // row = 16 uint4
    float acc[8];
#pragma unroll
    for (int j = 0; j < 8; j++) acc[j] = 0.f;
    float rsl = 0.f;
    int last = s1 - 1;
    for (int e = s0; e < s1; e += 8) {
        int eA = e + q;
        int eB = e + 4 + q;
        int iA = eA <= last ? eA : last;
        int iB = eB <= last ? eB : last;
        int dA = edst[iA];
        int dB = edst[iB];
        float evA = esv + ed_[dA];
        float evB = esv + ed_[dB];
        uint4 rA = Hq[(size_t)dA * 16 + f16];
        uint4 rB = Hq[(size_t)dB * 16 + f16];
        float lrA = evA > 0.f ? evA : 0.2f * evA;
        float lrB = evB > 0.f ? evB : 0.2f * evB;
        float wA = __expf(-lrA);
        float wB = __expf(-lrB);
        if (eA > last) wA = 0.f;
        if (eB > last) wB = 0.f;
        rsl += wA + wB;
        unsigned int ra[4] = {rA.x, rA.y, rA.z, rA.w};
        unsigned int rb[4] = {rB.x, rB.y, rB.z, rB.w};
#pragma unroll
        for (int k = 0; k < 4; k++) {
            acc[2 * k]     += wA * __uint_as_float(ra[k] << 16)
                            + wB * __uint_as_float(rb[k] << 16);
            acc[2 * k + 1] += wA * __uint_as_float(ra[k] & 0xffff0000u)
                            + wB * __uint_as_float(rb[k] & 0xffff0000u);
        }
    }
    // reduce across the 4 lane-quarters (lanes ^16, ^32)
    float rs = rsl;
    rs += __shfl_xor(rs, 16);
    rs += __shfl_xor(rs, 32);
#pragma unroll
    for (int j = 0; j < 8; j++) {
        acc[j] += __shfl_xor(acc[j], 16);
        acc[j] += __shfl_xor(acc[j], 32);
    }
    float inv = 1.f / (rs + 1e-16f);
    unsigned int pk[4];
#pragma unroll
    for (int k = 0; k < 4; k++) {
        float v0 = acc[2 * k] * inv;
        float v1 = acc[2 * k + 1] * inv;
        v0 = v0 > 0.f ? v0 : (__expf(v0) - 1.f);   // elu, alpha=1
        v1 = v1 > 0.f ? v1 : (__expf(v1) - 1.f);
        pk[k] = ((unsigned int)f2bf(v1) << 16) | f2bf(v0);
    }
    if (q == 0) {
        uint4 o = make_uint4(pk[0], pk[1], pk[2], pk[3]);
        ((uint4*)(Out + (size_t)node * FD))[f16] = o;
    }
}

// ---------------------------------------------------------------- BN stats (bf16 input, unchanged)
__global__ void bnstats_b_k(const u16* __restrict__ Xb, float* __restrict__ sums,
                            float* __restrict__ sumsq, int M) {
    int f = threadIdx.x & 127;
    int half = threadIdx.x >> 7;
    float s1 = 0.f, s2 = 0.f;
    for (int r = blockIdx.x * 2 + half; r < M; r += gridDim.x * 2) {
        float v = bf2f(Xb[(size_t)r * FD + f]);
        s1 += v; s2 += v * v;
    }
    __shared__ float l1[256], l2[256];
    l1[threadIdx.x] = s1; l2[threadIdx.x] = s2;
    __syncthreads();
    if (half == 0) {
        atomicAdd(&sums[f], l1[f] + l1[f + 128]);
        atomicAdd(&sumsq[f], l2[f] + l2[f + 128]);
    }
}

// ---------------------------------------------------------------- pooling + MLP: ONE coop kernel
__global__ __launch_bounds__(256) void poolmlp_coop_k(const u16* __restrict__ Xb,
                                                      const int* __restrict__ gi,
                                                      float* __restrict__ pooled,
                                                      const float* __restrict__ fc1w,
                                                      const float* __restrict__ fc1b,
                                                      const float* __restrict__ fc2w,
                                                      const float* __restrict__ fc2b,
                                                      const float* __restrict__ fc3w,
                                                      const float* __restrict__ fc3b,
                                                      float* __restrict__ out, int M) {
    cg::grid_group grid = cg::this_grid();
    int tid = threadIdx.x;
    // ---- phase 1: pooling (grid-stride over 128-row chunks)
    {
        int f = tid & 127;
        int half = tid >> 7;
        int NC = (M + 127) / 128;
        for (int c = blockIdx.x; c < NC; c += gridDim.x) {
            int r0 = c * 128 + half;
            int rend = min(c * 128 + 128, M);
            int curg = -1; float acc = 0.f;
            for (int r = r0; r < rend; r += 2) {
                int g = gi[r];
                if (g != curg) {
                    if (curg >= 0) atomicAdd(&pooled[(size_t)curg * FD + f], acc);
                    curg = g; acc = 0.f;
                }
                acc += bf2f(Xb[(size_t)r * FD + f]);
            }
            if (curg >= 0) atomicAdd(&pooled[(size_t)curg * FD + f], acc);
        }
    }
    grid.sync();
    // ---- phase 2: MLP (one block per graph; grid == N_GRAPHS)
    int g = blockIdx.x, j = tid;
    __shared__ float x[128], t1[256], t2[128], p0[128], p1[128];
    if (j < 128) x[j] = pooled[(size_t)g * FD + j];
    __syncthreads();
    float s = fc1b[j];
    for (int k = 0; k < 128; k++) s += x[k] * fc1w[(size_t)k * 256 + j];
    t1[j] = fmaxf(s, 0.f);
    __syncthreads();
    if (j < 128) {
        float s2 = fc2b[j];
        for (int k = 0; k < 256; k++) s2 += t1[k] * fc2w[(size_t)k * 128 + j];
        t2[j] = fmaxf(s2, 0.f);
    }
    __syncthreads();
    if (j < 128) { p0[j] = t2[j] * fc3w[j * 2]; p1[j] = t2[j] * fc3w[j * 2 + 1]; }
    __syncthreads();
    for (int s3 = 64; s3 > 0; s3 >>= 1) {
        if (j < s3) { p0[j] += p0[j + s3]; p1[j] += p1[j + s3]; }
        __syncthreads();
    }
    if (j == 0) { out[g * 2] = p0[0] + fc3b[0]; out[g * 2 + 1] = p1[0] + fc3b[1]; }
}

// ---------------------------------------------------------------- classic pool/mlp (fallback only)
__global__ void pool_k(const u16* __restrict__ Xb, const int* __restrict__ gi,
                       float* __restrict__ pooled, int M) {
    int f = threadIdx.x & 127;
    int half = threadIdx.x >> 7;
    int r0 = blockIdx.x * 128 + half;
    int rend = min(blockIdx.x * 128 + 128, M);
    int curg = -1; float acc = 0.f;
    for (int r = r0; r < rend; r += 2) {
        int g = gi[r];
        if (g != curg) {
            if (curg >= 0) atomicAdd(&pooled[(size_t)curg * FD + f], acc);
            curg = g; acc = 0.f;
        }
        acc += bf2f(Xb[(size_t)r * FD + f]);
    }
    if (curg >= 0) atomicAdd(&pooled[(size_t)curg * FD + f], acc);
}
__global__ __launch_bounds__(256) void mlp_k(const float* __restrict__ pooled,
                                             const float* __restrict__ fc1w, const float* __restrict__ fc1b,
                                             const float* __restrict__ fc2w, const float* __restrict__ fc2b,
                                             const float* __restrict__ fc3w, const float* __restrict__ fc3b,
                                             float* __restrict__ out) {
    int g = blockIdx.x, j = threadIdx.x;
    __shared__ float x[128], t1[256], t2[128], p0[128], p1[128];
    if (j < 128) x[j] = pooled[(size_t)g * FD + j];
    __syncthreads();
    float s = fc1b[j];
    for (int k = 0; k < 128; k++) s += x[k] * fc1w[(size_t)k * 256 + j];
    t1[j] = fmaxf(s, 0.f);
    __syncthreads();
    if (j < 128) {
        float s2 = fc2b[j];
        for (int k = 0; k < 256; k++) s2 += t1[k] * fc2w[(size_t)k * 128 + j];
        t2[j] = fmaxf(s2, 0.f);
    }
    __syncthreads();
    if (j < 128) { p0[j] = t2[j] * fc3w[j * 2]; p1[j] = t2[j] * fc3w[j * 2 + 1]; }
    __syncthreads();
    for (int s3 = 64; s3 > 0; s3 >>= 1) {
        if (j < s3) { p0[j] += p0[j + s3]; p1[j] += p1[j + s3]; }
        __syncthreads();
    }
    if (j == 0) { out[g * 2] = p0[0] + fc3b[0]; out[g * 2 + 1] = p1[0] + fc3b[1]; }
}

// ---------------------------------------------------------------- launcher
extern "C" void kernel_launch(void* const* d_in, const int* in_sizes, int n_in,
                              void* d_out, int out_size, void* d_ws, size_t ws_size,
                              hipStream_t stream) {
    const int*   adj  = (const int*)d_in[0];
    const float* xin  = (const float*)d_in[1];
    const int*   gi   = (const int*)d_in[2];
    const float* W1   = (const float*)d_in[4];
    const float* a1   = (const float*)d_in[5];
    const float* bn2g = (const float*)d_in[6];
    const float* bn2b = (const float*)d_in[7];
    const float* W2   = (const float*)d_in[8];
    const float* a2   = (const float*)d_in[9];
    const float* bn3g = (const float*)d_in[10];
    const float* bn3b = (const float*)d_in[11];
    const float* W3   = (const float*)d_in[12];
    const float* a3   = (const float*)d_in[13];
    const float* fc1w = (const float*)d_in[14];
    const float* fc1b = (const float*)d_in[15];
    const float* fc2w = (const float*)d_in[16];
    const float* fc2b = (const float*)d_in[17];
    const float* fc3w = (const float*)d_in[18];
    const float* fc3b = (const float*)d_in[19];
    float* out = (float*)d_out;

    const int N = N_NODES, E = N_EDGES, G = N_GRAPHS;

    u16*   Xb     = (u16*)d_ws;                   // [N,128] bf16 node features
    u16*   Hb     = Xb + (size_t)N * FD;          // [N,128] bf16 post-GEMM
    u16*   Wt     = Hb + (size_t)N * FD;          // [128,128] (unused, kept for layout)
    float* es     = (float*)(Wt + FD * FD);       // [N]
    float* ed     = es + N;                       // [N]
    float* bnbuf  = ed + N;                       // [512]: sumsA, sumsqA, sumsB, sumsqB
    float* sumsA  = bnbuf;
    float* sumsqA = bnbuf + 128;
    float* sumsB  = bnbuf + 256;
    float* sumsqB = bnbuf + 384;
    float* cvec   = bnbuf + 512;                  // [128] (unused, kept for layout)
    float* pooled = cvec + FD;                    // [G,128]
    int*   degcnt = (int*)(pooled + (size_t)G * FD); // [N]
    int*   offs   = degcnt + N;                   // [N+1] (padded to N+2)
    int*   cur    = offs + (N + 2);               // [N]
    int*   bsum   = cur + N;                      // [256]
    int*   edst   = bsum + 256;                   // [E] dst per CSR slot

    const int* srcp = adj;
    const int* dstp = adj + E;

    const int NB = (N + 255) / 256;

    // ---- CSR build + zeroing: single cooperative kernel (fallback: classic 5-dispatch path)
    {
        int Ei = E, Ni = N, NBi = NB;
        void* args[] = {(void*)&srcp, (void*)&dstp, (void*)&degcnt, (void*)&bsum,
                        (void*)&offs, (void*)&cur, (void*)&edst, (void*)&bnbuf,
                        (void*)&pooled, (void*)&Ei, (void*)&Ni, (void*)&NBi};
        hipError_t err = hipLaunchCooperativeKernel((const void*)csr_coop_k,
                                                    dim3(1024), dim3(256), args, 0, stream);
        if (err != hipSuccess) {
            zero_k<<<256, 256, 0, stream>>>(degcnt, bnbuf, pooled, N);
            count_deg_part_k<<<8 * 392, 256, 0, stream>>>(srcp, degcnt, E);
            scan1_k<<<NB, 256, 0, stream>>>(degcnt, bsum, N);
            scan3_k<<<NB, 256, 0, stream>>>(degcnt, bsum, offs, cur, N, NB);
            fill_csr_part_k<<<8 * 392, 256, 0, stream>>>(srcp, dstp, cur, edst, E);
        }
    }

    const int gemm_grid = (N + 63) / 64;
    const int wave_grid = (N + 3) / 4;      // 4 waves per 256-thread block
    const float invN = 1.0f / (float)N;

    // ---- layer 1 (fp32 input staged directly; identity affine; wprep fused in gemm)
    gemm_mfma_k<<<gemm_grid, 256, 0, stream>>>(xin, Xb, 1, W1,
                                               nullptr, nullptr, nullptr, nullptr, invN, 0,
                                               a1, Hb, es, ed, N);
    agg_k<<<wave_grid, 256, 0, stream>>>(Hb, es, ed, offs, edst, Xb, N);
    bnstats_b_k<<<256, 256, 0, stream>>>(Xb, sumsA, sumsqA, N);

    // ---- layer 2 (BN fold fused in gemm)
    gemm_mfma_k<<<gemm_grid, 256, 0, stream>>>(nullptr, Xb, 0, W2,
                                               sumsA, sumsqA, bn2g, bn2b, invN, 1,
                                               a2, Hb, es, ed, N);
    agg_k<<<wave_grid, 256, 0, stream>>>(Hb, es, ed, offs, edst, Xb, N);
    bnstats_b_k<<<256, 256, 0, stream>>>(Xb, sumsB, sumsqB, N);

    // ---- layer 3
    gemm_mfma_k<<<gemm_grid, 256, 0, stream>>>(nullptr, Xb, 0, W3,
                                               sumsB, sumsqB, bn3g, bn3b, invN, 1,
                                               a3, Hb, es, ed, N);
    agg_k<<<wave_grid, 256, 0, stream>>>(Hb, es, ed, offs, edst, Xb, N);

    // ---- pooling + MLP: single cooperative kernel (fallback: classic 2-dispatch path)
    {
        int Ni = N;
        void* args[] = {(void*)&Xb, (void*)&gi, (void*)&pooled,
                        (void*)&fc1w, (void*)&fc1b, (void*)&fc2w, (void*)&fc2b,
                        (void*)&fc3w, (void*)&fc3b, (void*)&out, (void*)&Ni};
        hipError_t err = hipLaunchCooperativeKernel((const void*)poolmlp_coop_k,
                                                    dim3(G), dim3(256), args, 0, stream);
        if (err != hipSuccess) {
            pool_k<<<(N + 127) / 128, 256, 0, stream>>>(Xb, gi, pooled, N);
            mlp_k<<<G, 256, 0, stream>>>(pooled, fc1w, fc1b, fc2w, fc2b, fc3w, fc3b, out);
        }
    }
}

// Round 9
// 421.326 us; speedup vs baseline: 2.0431x; 2.0431x over previous
//
#include <hip/hip_runtime.h>
#include <hip/hip_bf16.h>

#define N_NODES 50000
#define N_EDGES 800000
#define FD 128
#define N_GRAPHS 256
#define NPART 6250   // N_NODES / 8 (nodes per XCD partition)

typedef unsigned short u16;
typedef short bf16x8 __attribute__((ext_vector_type(8)));
typedef float f32x4 __attribute__((ext_vector_type(4)));

__device__ __forceinline__ u16 f2bf(float v) {
    __hip_bfloat16 h = __float2bfloat16(v);
    union { __hip_bfloat16 hh; u16 u; } c; c.hh = h; return c.u;
}
__device__ __forceinline__ float bf2f(u16 r) {
    return __uint_as_float(((unsigned int)r) << 16);
}

// ---------------------------------------------------------------- CSR build (XCD-partitioned)
__global__ __launch_bounds__(256) void count_deg_part_k(const int* __restrict__ src,
                                                        int* __restrict__ cnt, int E) {
    int part = blockIdx.x & 7;
    int lo = part * NPART, hi = lo + NPART;
    int stride = (gridDim.x >> 3) * 256;
    for (int e = (blockIdx.x >> 3) * 256 + threadIdx.x; e < E; e += stride) {
        int s = src[e];
        if (s >= lo && s < hi) atomicAdd(&cnt[s], 1);
    }
}

__global__ __launch_bounds__(256) void fill_csr_part_k(const int* __restrict__ src,
                                                       const int* __restrict__ dst,
                                                       int* __restrict__ cur,
                                                       int* __restrict__ edst, int E) {
    int part = blockIdx.x & 7;
    int lo = part * NPART, hi = lo + NPART;
    int stride = (gridDim.x >> 3) * 256;
    for (int e = (blockIdx.x >> 3) * 256 + threadIdx.x; e < E; e += stride) {
        int s = src[e];
        if (s >= lo && s < hi) {
            int p = atomicAdd(&cur[s], 1);
            edst[p] = dst[e];
        }
    }
}

// per-256-chunk sums; block 0 also zeroes bnbuf (512 f) and pooled (32768 f)
__global__ __launch_bounds__(256) void scan1_k(const int* __restrict__ cnt,
                                               int* __restrict__ bsum, int M,
                                               float* __restrict__ bnbuf,
                                               float* __restrict__ pooled) {
    int i = blockIdx.x * 256 + threadIdx.x;
    int v = (i < M) ? cnt[i] : 0;
    __shared__ int l[256];
    l[threadIdx.x] = v;
    __syncthreads();
    for (int s = 128; s > 0; s >>= 1) {
        if (threadIdx.x < s) l[threadIdx.x] += l[threadIdx.x + s];
        __syncthreads();
    }
    if (threadIdx.x == 0) bsum[blockIdx.x] = l[0];
    if (blockIdx.x == 0) {
        bnbuf[threadIdx.x] = 0.f; bnbuf[threadIdx.x + 256] = 0.f;
        for (int k = threadIdx.x; k < N_GRAPHS * FD; k += 256) pooled[k] = 0.f;
    }
}

// local exclusive scan + redundant per-block scan of raw bsum (merged scan2)
__global__ __launch_bounds__(256) void scan3_k(const int* __restrict__ cnt,
                                               const int* __restrict__ bsum,
                                               int* __restrict__ offs,
                                               int* __restrict__ cur, int M, int NB) {
    int i = blockIdx.x * 256 + threadIdx.x;
    int tid = threadIdx.x;
    __shared__ int bs[256];
    bs[tid] = (tid < NB) ? bsum[tid] : 0;
    __syncthreads();
    for (int off = 1; off < 256; off <<= 1) {
        int t = (tid >= off) ? bs[tid - off] : 0;
        __syncthreads();
        bs[tid] += t;
        __syncthreads();
    }
    int base = (blockIdx.x == 0) ? 0 : bs[blockIdx.x - 1];
    int v = (i < M) ? cnt[i] : 0;
    __shared__ int l[256];
    l[tid] = v;
    __syncthreads();
    for (int off = 1; off < 256; off <<= 1) {
        int t = (tid >= off) ? l[tid - off] : 0;
        __syncthreads();
        l[tid] += t;
        __syncthreads();
    }
    int excl = l[tid] - v + base;
    if (i < M) { offs[i] = excl; cur[i] = excl; }
    if (i == M - 1) offs[M] = excl + v;
}

// ---------------------------------------------------------------- weight prep (one-shot per layer)
// layer 1 (no affine): Wt[n][k] = bf16(W[k][n]); cvec = 0
__global__ __launch_bounds__(128) void wprep1_k(const float* __restrict__ W,
                                                u16* __restrict__ Wt,
                                                float* __restrict__ cvec) {
    int n = blockIdx.x, k = threadIdx.x;
    Wt[(size_t)n * FD + k] = f2bf(W[(size_t)k * FD + n]);
    if (k == 0) cvec[n] = 0.f;
}

// layers 2/3: BN finalize (redundant per block, from sums/sumsq) + weight fold
__global__ __launch_bounds__(128) void bnfw_k(const float* __restrict__ W,
                                              const float* __restrict__ sums,
                                              const float* __restrict__ sumsq,
                                              const float* __restrict__ g,
                                              const float* __restrict__ b,
                                              float invN,
                                              u16* __restrict__ Wt,
                                              float* __restrict__ cvec) {
    int n = blockIdx.x, k = threadIdx.x;
    __shared__ float scs[128], shs[128], l[128];
    float mu = sums[k] * invN;
    float var = sumsq[k] * invN - mu * mu;
    float sc = g[k] * rsqrtf(var + 1e-5f);
    scs[k] = sc;
    shs[k] = b[k] - mu * sc;
    __syncthreads();
    float w = W[(size_t)k * FD + n];
    Wt[(size_t)n * FD + k] = f2bf(scs[k] * w);
    l[k] = shs[k] * w;
    __syncthreads();
    for (int s = 64; s > 0; s >>= 1) {
        if (k < s) l[k] += l[k + s];
        __syncthreads();
    }
    if (k == 0) cvec[n] = l[0];
}

// ---------------------------------------------------------------- MFMA GEMM + dots
// (R0-style vectorized Bs staging from pre-folded Wt; avec dots in registers)
__global__ __launch_bounds__(256) void gemm_mfma_k(const float* __restrict__ Xf,
                                                   const u16* __restrict__ Xb,
                                                   int use_f32,
                                                   const u16* __restrict__ Wt,
                                                   const float* __restrict__ cvec,
                                                   const float* __restrict__ avec,
                                                   u16* __restrict__ Hb,
                                                   float* __restrict__ es,
                                                   float* __restrict__ ed, int M) {
    __shared__ u16 As[64][136];   // +8 pad: 2-way bank alias only
    __shared__ u16 Bs[128][136];
    __shared__ float cv[128];
    int tid = threadIdx.x;
    int row0 = blockIdx.x * 64;
    if (tid < 128) cv[tid] = cvec[tid];
    {
        int n = tid >> 1, k0 = (tid & 1) * 64;
        const uint4* s = (const uint4*)(Wt + (size_t)n * FD + k0);
#pragma unroll
        for (int u = 0; u < 8; u++) *(uint4*)&Bs[n][k0 + u * 8] = s[u];
    }
    {
        int r = tid >> 2, k0 = (tid & 3) * 32;
        int grow = row0 + r;
        if (grow < M) {
            if (use_f32) {
                const float4* s = (const float4*)(Xf + (size_t)grow * FD + k0);
#pragma unroll
                for (int u = 0; u < 8; u++) {
                    float4 v = s[u];
                    ushort4 o;
                    o.x = f2bf(v.x); o.y = f2bf(v.y); o.z = f2bf(v.z); o.w = f2bf(v.w);
                    *(ushort4*)&As[r][k0 + u * 4] = o;
                }
            } else {
                const uint4* s = (const uint4*)(Xb + (size_t)grow * FD + k0);
#pragma unroll
                for (int u = 0; u < 4; u++) *(uint4*)&As[r][k0 + u * 8] = s[u];
            }
        } else {
            uint4 z = make_uint4(0, 0, 0, 0);
#pragma unroll
            for (int u = 0; u < 4; u++) *(uint4*)&As[r][k0 + u * 8] = z;
        }
    }
    __syncthreads();

    int wave = tid >> 6, lane = tid & 63;
    int quad = lane >> 4, n16 = lane & 15;
    int rbase = wave * 16;
    f32x4 acc[8];
    f32x4 zz = {0.f, 0.f, 0.f, 0.f};
#pragma unroll
    for (int t = 0; t < 8; t++) acc[t] = zz;

#pragma unroll
    for (int kk = 0; kk < 128; kk += 32) {
        bf16x8 a = *(const bf16x8*)&As[rbase + n16][kk + quad * 8];
#pragma unroll
        for (int t = 0; t < 8; t++) {
            bf16x8 bb = *(const bf16x8*)&Bs[t * 16 + n16][kk + quad * 8];
            acc[t] = __builtin_amdgcn_mfma_f32_16x16x32_bf16(a, bb, acc[t], 0, 0, 0);
        }
    }

    float sas[8], sad[8];
#pragma unroll
    for (int t = 0; t < 8; t++) {
        sas[t] = avec[t * 16 + n16];
        sad[t] = avec[128 + t * 16 + n16];
    }

#pragma unroll
    for (int reg = 0; reg < 4; reg++) {
        int grow = row0 + rbase + quad * 4 + reg;
        float vals[8];
        float ps = 0.f, pd = 0.f;
#pragma unroll
        for (int t = 0; t < 8; t++) {
            float v = acc[t][reg] + cv[t * 16 + n16];
            vals[t] = v;
            ps += v * sas[t];
            pd += v * sad[t];
        }
#pragma unroll
        for (int o = 8; o > 0; o >>= 1) { ps += __shfl_xor(ps, o); pd += __shfl_xor(pd, o); }
        if (grow < M) {
            if (n16 == 0) { es[grow] = ps; ed[grow] = pd; }
#pragma unroll
            for (int t = 0; t < 8; t++)
                Hb[(size_t)grow * FD + t * 16 + n16] = f2bf(vals[t]);
        }
    }
}

// ---------------------------------------------------------------- fused aggregation (R6 proven:
// lane-quartered, 7 args, no atomics)
__global__ __launch_bounds__(256) void agg_k(const u16* __restrict__ Hb,
                                             const float* __restrict__ es_,
                                             const float* __restrict__ ed_,
                                             const int* __restrict__ offs,
                                             const int* __restrict__ edst,
                                             u16* __restrict__ Out, int M) {
    int node = __builtin_amdgcn_readfirstlane((int)((blockIdx.x * blockDim.x + threadIdx.x) >> 6));
    int lane = threadIdx.x & 63;
    if (node >= M) return;
    int s0 = offs[node], s1 = offs[node + 1];
    float esv = es_[node];
    int q = lane >> 4;       // edge slot within group
    int f16 = lane & 15;     // 16B-chunk index within row
    const uint4* Hq = (const uint4*)Hb;   // row = 16 uint4
    float acc[8];
#pragma unroll
    for (int j = 0; j < 8; j++) acc[j] = 0.f;
    float rsl = 0.f;
    int last = s1 - 1;
    for (int e = s0; e < s1; e += 8) {
        int eA = e + q;
        int eB = e + 4 + q;
        int iA = eA <= last ? eA : last;
        int iB = eB <= last ? eB : last;
        int dA = edst[iA];
        int dB = edst[iB];
        float evA = esv + ed_[dA];
        float evB = esv + ed_[dB];
        uint4 rA = Hq[(size_t)dA * 16 + f16];
        uint4 rB = Hq[(size_t)dB * 16 + f16];
        float lrA = evA > 0.f ? evA : 0.2f * evA;
        float lrB = evB > 0.f ? evB : 0.2f * evB;
        float wA = __expf(-lrA);
        float wB = __expf(-lrB);
        if (eA > last) wA = 0.f;
        if (eB > last) wB = 0.f;
        rsl += wA + wB;
        unsigned int ra[4] = {rA.x, rA.y, rA.z, rA.w};
        unsigned int rb[4] = {rB.x, rB.y, rB.z, rB.w};
#pragma unroll
        for (int k = 0; k < 4; k++) {
            acc[2 * k]     += wA * __uint_as_float(ra[k] << 16)
                            + wB * __uint_as_float(rb[k] << 16);
            acc[2 * k + 1] += wA * __uint_as_float(ra[k] & 0xffff0000u)
                            + wB * __uint_as_float(rb[k] & 0xffff0000u);
        }
    }
    // reduce across the 4 lane-quarters (lanes ^16, ^32)
    float rs = rsl;
    rs += __shfl_xor(rs, 16);
    rs += __shfl_xor(rs, 32);
#pragma unroll
    for (int j = 0; j < 8; j++) {
        acc[j] += __shfl_xor(acc[j], 16);
        acc[j] += __shfl_xor(acc[j], 32);
    }
    float inv = 1.f / (rs + 1e-16f);
    unsigned int pk[4];
#pragma unroll
    for (int k = 0; k < 4; k++) {
        float v0 = acc[2 * k] * inv;
        float v1 = acc[2 * k + 1] * inv;
        v0 = v0 > 0.f ? v0 : (__expf(v0) - 1.f);   // elu, alpha=1
        v1 = v1 > 0.f ? v1 : (__expf(v1) - 1.f);
        pk[k] = ((unsigned int)f2bf(v1) << 16) | f2bf(v0);
    }
    if (q == 0) {
        uint4 o = make_uint4(pk[0], pk[1], pk[2], pk[3]);
        ((uint4*)(Out + (size_t)node * FD))[f16] = o;
    }
}

// ---------------------------------------------------------------- BN stats (bf16 input)
__global__ void bnstats_b_k(const u16* __restrict__ Xb, float* __restrict__ sums,
                            float* __restrict__ sumsq, int M) {
    int f = threadIdx.x & 127;
    int half = threadIdx.x >> 7;
    float s1 = 0.f, s2 = 0.f;
    for (int r = blockIdx.x * 2 + half; r < M; r += gridDim.x * 2) {
        float v = bf2f(Xb[(size_t)r * FD + f]);
        s1 += v; s2 += v * v;
    }
    __shared__ float l1[256], l2[256];
    l1[threadIdx.x] = s1; l2[threadIdx.x] = s2;
    __syncthreads();
    if (half == 0) {
        atomicAdd(&sums[f], l1[f] + l1[f + 128]);
        atomicAdd(&sumsq[f], l2[f] + l2[f + 128]);
    }
}

// ---------------------------------------------------------------- pooling (sorted graph ids, bf16 in)
__global__ void pool_k(const u16* __restrict__ Xb, const int* __restrict__ gi,
                       float* __restrict__ pooled, int M) {
    int f = threadIdx.x & 127;
    int half = threadIdx.x >> 7;
    int r0 = blockIdx.x * 128 + half;
    int rend = min(blockIdx.x * 128 + 128, M);
    int curg = -1; float acc = 0.f;
    for (int r = r0; r < rend; r += 2) {
        int g = gi[r];
        if (g != curg) {
            if (curg >= 0) atomicAdd(&pooled[(size_t)curg * FD + f], acc);
            curg = g; acc = 0.f;
        }
        acc += bf2f(Xb[(size_t)r * FD + f]);
    }
    if (curg >= 0) atomicAdd(&pooled[(size_t)curg * FD + f], acc);
}

// ---------------------------------------------------------------- fused MLP (one block per graph)
__global__ __launch_bounds__(256) void mlp_k(const float* __restrict__ pooled,
                                             const float* __restrict__ fc1w, const float* __restrict__ fc1b,
                                             const float* __restrict__ fc2w, const float* __restrict__ fc2b,
                                             const float* __restrict__ fc3w, const float* __restrict__ fc3b,
                                             float* __restrict__ out) {
    int g = blockIdx.x, j = threadIdx.x;
    __shared__ float x[128], t1[256], t2[128], p0[128], p1[128];
    if (j < 128) x[j] = pooled[(size_t)g * FD + j];
    __syncthreads();
    float s = fc1b[j];
    for (int k = 0; k < 128; k++) s += x[k] * fc1w[(size_t)k * 256 + j];
    t1[j] = fmaxf(s, 0.f);
    __syncthreads();
    if (j < 128) {
        float s2 = fc2b[j];
        for (int k = 0; k < 256; k++) s2 += t1[k] * fc2w[(size_t)k * 128 + j];
        t2[j] = fmaxf(s2, 0.f);
    }
    __syncthreads();
    if (j < 128) { p0[j] = t2[j] * fc3w[j * 2]; p1[j] = t2[j] * fc3w[j * 2 + 1]; }
    __syncthreads();
    for (int s3 = 64; s3 > 0; s3 >>= 1) {
        if (j < s3) { p0[j] += p0[j + s3]; p1[j] += p1[j + s3]; }
        __syncthreads();
    }
    if (j == 0) { out[g * 2] = p0[0] + fc3b[0]; out[g * 2 + 1] = p1[0] + fc3b[1]; }
}

// ---------------------------------------------------------------- launcher
extern "C" void kernel_launch(void* const* d_in, const int* in_sizes, int n_in,
                              void* d_out, int out_size, void* d_ws, size_t ws_size,
                              hipStream_t stream) {
    const int*   adj  = (const int*)d_in[0];
    const float* xin  = (const float*)d_in[1];
    const int*   gi   = (const int*)d_in[2];
    const float* W1   = (const float*)d_in[4];
    const float* a1   = (const float*)d_in[5];
    const float* bn2g = (const float*)d_in[6];
    const float* bn2b = (const float*)d_in[7];
    const float* W2   = (const float*)d_in[8];
    const float* a2   = (const float*)d_in[9];
    const float* bn3g = (const float*)d_in[10];
    const float* bn3b = (const float*)d_in[11];
    const float* W3   = (const float*)d_in[12];
    const float* a3   = (const float*)d_in[13];
    const float* fc1w = (const float*)d_in[14];
    const float* fc1b = (const float*)d_in[15];
    const float* fc2w = (const float*)d_in[16];
    const float* fc2b = (const float*)d_in[17];
    const float* fc3w = (const float*)d_in[18];
    const float* fc3b = (const float*)d_in[19];
    float* out = (float*)d_out;

    const int N = N_NODES, E = N_EDGES, G = N_GRAPHS;

    u16*   Xb     = (u16*)d_ws;                   // [N,128] bf16 node features
    u16*   Hb     = Xb + (size_t)N * FD;          // [N,128] bf16 post-GEMM
    u16*   Wt     = Hb + (size_t)N * FD;          // [128,128] bf16 transposed, BN-folded
    float* es     = (float*)(Wt + FD * FD);       // [N]
    float* ed     = es + N;                       // [N]
    float* bnbuf  = ed + N;                       // [512]: sumsA, sumsqA, sumsB, sumsqB
    float* sumsA  = bnbuf;
    float* sumsqA = bnbuf + 128;
    float* sumsB  = bnbuf + 256;
    float* sumsqB = bnbuf + 384;
    float* cvec   = bnbuf + 512;                  // [128]
    float* pooled = cvec + FD;                    // [G,128]
    int*   degcnt = (int*)(pooled + (size_t)G * FD); // [N]
    int*   offs   = degcnt + N;                   // [N+1] (padded to N+2)
    int*   cur    = offs + (N + 2);               // [N]
    int*   bsum   = cur + N;                      // [256]
    int*   edst   = bsum + 256;                   // [E] dst per CSR slot

    const int* srcp = adj;
    const int* dstp = adj + E;

    const int NB = (N + 255) / 256;

    // ---- CSR build (once; reused by all 3 layers) — XCD-partitioned
    hipMemsetAsync(degcnt, 0, (size_t)N * sizeof(int), stream);
    count_deg_part_k<<<8 * 392, 256, 0, stream>>>(srcp, degcnt, E);
    scan1_k<<<NB, 256, 0, stream>>>(degcnt, bsum, N, bnbuf, pooled);
    scan3_k<<<NB, 256, 0, stream>>>(degcnt, bsum, offs, cur, N, NB);
    fill_csr_part_k<<<8 * 392, 256, 0, stream>>>(srcp, dstp, cur, edst, E);

    const int gemm_grid = (N + 63) / 64;
    const int wave_grid = (N + 3) / 4;      // 4 waves per 256-thread block
    const float invN = 1.0f / (float)N;

    // ---- layer 1 (fp32 input staged directly; identity affine; one-shot weight prep)
    wprep1_k<<<FD, 128, 0, stream>>>(W1, Wt, cvec);
    gemm_mfma_k<<<gemm_grid, 256, 0, stream>>>(xin, Xb, 1, Wt, cvec, a1, Hb, es, ed, N);
    agg_k<<<wave_grid, 256, 0, stream>>>(Hb, es, ed, offs, edst, Xb, N);
    bnstats_b_k<<<256, 256, 0, stream>>>(Xb, sumsA, sumsqA, N);

    // ---- layer 2 (BN folded into Wt/cvec once)
    bnfw_k<<<FD, 128, 0, stream>>>(W2, sumsA, sumsqA, bn2g, bn2b, invN, Wt, cvec);
    gemm_mfma_k<<<gemm_grid, 256, 0, stream>>>(nullptr, Xb, 0, Wt, cvec, a2, Hb, es, ed, N);
    agg_k<<<wave_grid, 256, 0, stream>>>(Hb, es, ed, offs, edst, Xb, N);
    bnstats_b_k<<<256, 256, 0, stream>>>(Xb, sumsB, sumsqB, N);

    // ---- layer 3
    bnfw_k<<<FD, 128, 0, stream>>>(W3, sumsB, sumsqB, bn3g, bn3b, invN, Wt, cvec);
    gemm_mfma_k<<<gemm_grid, 256, 0, stream>>>(nullptr, Xb, 0, Wt, cvec, a3, Hb, es, ed, N);
    agg_k<<<wave_grid, 256, 0, stream>>>(Hb, es, ed, offs, edst, Xb, N);

    // ---- pooling + MLP
    pool_k<<<(N + 127) / 128, 256, 0, stream>>>(Xb, gi, pooled, N);
    mlp_k<<<G, 256, 0, stream>>>(pooled, fc1w, fc1b, fc2w, fc2b, fc3w, fc3b, out);
}